// Round 8
// baseline (208.436 us; speedup 1.0000x reference)
//
#include <hip/hip_runtime.h>
#include <hip/hip_bf16.h>
#include <stdint.h>

#define Bb 16
#define Nn 1024
#define Hh 8
#define Dd 64

typedef unsigned short u16;
typedef float f32x4 __attribute__((ext_vector_type(4)));
typedef short short8 __attribute__((ext_vector_type(8)));

union U4S8 { uint4 u; short8 s; };
union BF2U { __hip_bfloat162 h; uint32_t u; };

__device__ __forceinline__ uint32_t f2bf(float f){
  union{float f;uint32_t i;} v; v.f=f;
  return (v.i + 0x7fffu + ((v.i>>16)&1u))>>16;
}

__device__ __forceinline__ f32x4 mfma16(short8 a, short8 b, f32x4 c){
  return __builtin_amdgcn_mfma_f32_16x16x32_bf16(a,b,c,0,0,0);
}

// log2(10000)/32
#define ROPE_K 0.41524101186092030f
// 0.125 * log2(e)  (sm_scale folded with exp->exp2 conversion)
#define QS 0.18033688011112042f
#define NEGBIG -1.0e30f

__global__ void rope_table_kernel(float2* __restrict__ tab){
  int id = blockIdx.x*256 + threadIdx.x;      // (n, i)
  int n = id >> 5, i = id & 31;
  float inv = exp2f(-(float)i * ROPE_K);
  float a = (float)n * inv;
  float s, c; sincosf(a, &s, &c);
  tab[id] = make_float2(c, s);
}

// ============================================================
// Prepass -> fragment-linear layouts (per (bh,kt) block of 4096 u16):
//   Kf elem = kb*1024 + half*512 + quad*128 + l15*8 + j
//     holds K[key=kb*16+l15][d=half*32+quad*8+j] (roped)
//   Vf elem = s*1024 + half*512 + qd*128 + l15v*8 + j
//     holds V[d=s*16+l15v][slot=half*32+qd*8+j], slot(k) permutation:
//     slot = (k&1) | ((k>>4)&3)<<1 | ((k>>2)&3)<<3 | ((k>>1)&1)<<5
// ============================================================
__global__ __launch_bounds__(256) void prepass_kernel(
    const float* __restrict__ xk, const float* __restrict__ xv,
    const float2* __restrict__ tab,
    u16* __restrict__ Kf, u16* __restrict__ Vf)
{
  const int tid = threadIdx.x;
  const int bid = blockIdx.x;
  const int nt = bid & 15, h = (bid>>4)&7, b = bid>>7;
  const size_t bh = (size_t)b*Hh + h;
  const size_t tile = (bh<<4) + nt;            // (bh*16 + kt) blocks of 4096

  // ---- K rope -> fragment-linear ----
  {
    int r = tid>>2, c = (tid&3)<<4;
    int n = (nt<<6) + r;
    const float4* g = (const float4*)(xk + ((((size_t)b*Nn + n)*Hh + h)<<6) + c);
    float4 a0=g[0],a1=g[1],a2=g[2],a3=g[3];
    float xx[16] = {a0.x,a0.y,a0.z,a0.w, a1.x,a1.y,a1.z,a1.w,
                    a2.x,a2.y,a2.z,a2.w, a3.x,a3.y,a3.z,a3.w};
    uint32_t w[8];
    #pragma unroll
    for (int j=0;j<8;++j){
      int i = (c>>1)+j;
      float cs, sn;
      if (tab){ float2 t = tab[(n<<5)+i]; cs = t.x; sn = t.y; }
      else { float inv = exp2f(-(float)i * ROPE_K); sincosf((float)n*inv, &sn, &cs); }
      float x0 = xx[2*j], x1 = xx[2*j+1];
      float q0 = x0*cs - x1*sn;
      float q1 = x1*cs + x0*sn;
      w[j] = f2bf(q0) | (f2bf(q1)<<16);
    }
    int kb = r>>4, l15 = r&15;
    int half = c>>5, qd = (c>>3)&3;
    u16* base = Kf + (tile<<12);
    int dest0 = (kb<<10) + (half<<9) + (qd<<7) + (l15<<3);
    *(uint4*)(base + dest0)       = make_uint4(w[0],w[1],w[2],w[3]);
    *(uint4*)(base + dest0 + 128) = make_uint4(w[4],w[5],w[6],w[7]);
  }

  // ---- V transpose + key permute -> fragment-linear ----
  {
    int k = tid&63, ds = (tid>>6)<<4;
    int n = (nt<<6) + k;
    int slot = (k&1) | (((k>>4)&3)<<1) | (((k>>2)&3)<<3) | (((k>>1)&1)<<5);
    int half = slot>>5, qd = (slot>>3)&3, j = slot&7;
    const float4* g = (const float4*)(xv + ((((size_t)b*Nn + n)*Hh + h)<<6) + ds);
    float4 a0=g[0],a1=g[1],a2=g[2],a3=g[3];
    float vv[16] = {a0.x,a0.y,a0.z,a0.w, a1.x,a1.y,a1.z,a1.w,
                    a2.x,a2.y,a2.z,a2.w, a3.x,a3.y,a3.z,a3.w};
    u16* base = Vf + (tile<<12);
    #pragma unroll
    for (int jj=0;jj<16;++jj){
      int d = ds + jj;
      int s = d>>4, l15v = d&15;
      base[(s<<10) + (half<<9) + (qd<<7) + (l15v<<3) + j] = (u16)f2bf(vv[jj]);
    }
  }
}

// ============================================================
// Main attention: 1024 blocks, 256 threads, wave owns 32 q rows.
// NO LDS, NO barriers in the K-loop: each wave streams K/V MFMA
// fragments directly global->VGPR (fragment-linear => one coalesced
// 1KB dwordx4 per fragment, L2-resident via XCD-aware swizzle).
// Compiler software-pipelines loads across the unrolled kt loop.
// ============================================================
__global__ __launch_bounds__(256,4) void attn7_kernel(
    const float* __restrict__ xq, const u16* __restrict__ Kf,
    const u16* __restrict__ Vf, const int* __restrict__ vis,
    const float2* __restrict__ tab, float* __restrict__ out)
{
  const int tid  = threadIdx.x;
  const int lane = tid & 63;
  const int wave = tid >> 6;
  const int l15  = lane & 15;
  const int quad = lane >> 4;

  // ---- XCD-aware block decode (grid = 1024, 8 XCDs, 128 blocks/XCD) ----
  const int bid = blockIdx.x;
  const int xcd = bid & 7;          // dispatch: consecutive bids round-robin XCDs
  const int i   = bid >> 3;         // 0..127 within this XCD
  const int bh_ = (xcd<<4) | (i>>3);// 16 bh per XCD, 8 qt-blocks adjacent in time
  const int qt  = i & 7;
  const int h   = bh_ & 7;
  const int b   = bh_ >> 3;
  const size_t bh = (size_t)bh_;
  const int qbase = qt<<7;

  const int* visb = vis + b*Nn;
  const u16* Kfb = Kf + (bh<<16);   // 16 tiles * 4096
  const u16* Vfb = Vf + (bh<<16);

  // ---- roped Q B-frags in registers (QS folded) ----
  short8 qa[2][2];
  #pragma unroll
  for (int mb=0; mb<2; ++mb){
    int n = qbase + (wave<<5) + (mb<<4) + l15;
    const float* src = xq + ((((size_t)b*Nn + n)*Hh + h)<<6);
    #pragma unroll
    for (int half=0; half<2; ++half){
      int d0 = (half<<5) + (quad<<3);
      const float4* g = (const float4*)(src + d0);
      float4 u0 = g[0], u1 = g[1];
      float xx[8] = {u0.x,u0.y,u0.z,u0.w, u1.x,u1.y,u1.z,u1.w};
      uint32_t w[4];
      #pragma unroll
      for (int j=0;j<4;++j){
        int i2 = (d0>>1) + j;
        float cs, sn;
        if (tab){ float2 t = tab[(n<<5)+i2]; cs = t.x; sn = t.y; }
        else { float inv = exp2f(-(float)i2 * ROPE_K); sincosf((float)n*inv, &sn, &cs); }
        float x0 = xx[2*j], x1 = xx[2*j+1];
        float q0 = (x0*cs - x1*sn)*QS;
        float q1 = (x1*cs + x0*sn)*QS;
        w[j] = f2bf(q0) | (f2bf(q1)<<16);
      }
      U4S8 t; t.u = make_uint4(w[0],w[1],w[2],w[3]);
      qa[mb][half] = t.s;
    }
  }

  U4S8 ones_u; ones_u.u = make_uint4(0x3F803F80u,0x3F803F80u,0x3F803F80u,0x3F803F80u);
  const short8 ones = ones_u.s;

  f32x4 acc[2][4];
  f32x4 l_acc[2];
  #pragma unroll
  for (int mb=0;mb<2;++mb){
    l_acc[mb] = (f32x4){0.f,0.f,0.f,0.f};
    #pragma unroll
    for (int s=0;s<4;++s) acc[mb][s] = (f32x4){0.f,0.f,0.f,0.f};
  }

  const int fofs = lane<<3;         // fragment base: lane*8 elems (16B)

  #pragma unroll 2
  for (int kt=0; kt<16; ++kt){
    const u16* kg = Kfb + (kt<<12);
    const u16* vg = Vfb + (kt<<12);

    // ---- S^T = K Q^T per kb (bias C-init = mask), exp2+pack in-register ----
    uint32_t pk[4][2][2];           // [kb][h][mb]
    #pragma unroll
    for (int kb=0;kb<4;++kb){
      short8 kf0 = *(const short8*)(kg + (kb<<10) + fofs);
      short8 kf1 = *(const short8*)(kg + (kb<<10) + 512 + fofs);
      int4 vi = *(const int4*)&visb[(kt<<6)+(kb<<4)+(quad<<2)];
      f32x4 bias;
      bias.x = vi.x ? 0.f : NEGBIG;
      bias.y = vi.y ? 0.f : NEGBIG;
      bias.z = vi.z ? 0.f : NEGBIG;
      bias.w = vi.w ? 0.f : NEGBIG;
      #pragma unroll
      for (int mb=0;mb<2;++mb){
        f32x4 t = mfma16(kf0, qa[mb][0], bias);
        t = mfma16(kf1, qa[mb][1], t);
        float p0 = __builtin_amdgcn_exp2f(t.x);
        float p1 = __builtin_amdgcn_exp2f(t.y);
        float p2 = __builtin_amdgcn_exp2f(t.z);
        float p3 = __builtin_amdgcn_exp2f(t.w);
        BF2U e0; e0.h = __float22bfloat162_rn(make_float2(p0,p1));
        BF2U e1; e1.h = __float22bfloat162_rn(make_float2(p2,p3));
        pk[kb][0][mb] = e0.u;
        pk[kb][1][mb] = e1.u;
      }
    }

    // ---- assemble P A-frags (pure register repack) ----
    short8 pa[2][2];
    #pragma unroll
    for (int mb=0;mb<2;++mb){
      U4S8 a0; a0.u = make_uint4(pk[0][0][mb], pk[1][0][mb], pk[2][0][mb], pk[3][0][mb]);
      U4S8 a1; a1.u = make_uint4(pk[0][1][mb], pk[1][1][mb], pk[2][1][mb], pk[3][1][mb]);
      pa[mb][0] = a0.s; pa[mb][1] = a1.s;
    }

    // ---- l += P * ones (matrix pipe), O += P V ----
    #pragma unroll
    for (int mb=0;mb<2;++mb){
      l_acc[mb] = mfma16(pa[mb][0], ones, l_acc[mb]);
      l_acc[mb] = mfma16(pa[mb][1], ones, l_acc[mb]);
    }
    #pragma unroll
    for (int s=0;s<4;++s){
      short8 vb0 = *(const short8*)(vg + (s<<10) + fofs);
      short8 vb1 = *(const short8*)(vg + (s<<10) + 512 + fofs);
      #pragma unroll
      for (int mb=0;mb<2;++mb){
        acc[mb][s] = mfma16(pa[mb][0], vb0, acc[mb][s]);
        acc[mb][s] = mfma16(pa[mb][1], vb1, acc[mb][s]);
      }
    }
  }

  // ---- epilogue: l already per-q in C layout; normalize + store ----
  #pragma unroll
  for (int mb=0;mb<2;++mb){
    int4 qvi = *(const int4*)&visb[qbase + (wave<<5) + (mb<<4) + (quad<<2)];
    int qv[4] = {qvi.x, qvi.y, qvi.z, qvi.w};
    #pragma unroll
    for (int rr=0;rr<4;++rr){
      float lq = l_acc[mb][rr];
      float invl = (qv[rr] != 0 && lq > 0.f) ? 1.f/lq : 0.f;
      int qrow = qbase + (wave<<5) + (mb<<4) + (quad<<2) + rr;
      float* ob = out + ((((size_t)b*Nn + qrow)*Hh + h)<<6);
      #pragma unroll
      for (int s=0;s<4;++s)
        ob[(s<<4)+l15] = acc[mb][s][rr]*invl;
    }
  }
}

// ============================================================
// Fallback (R2 kernel, inline sincos) — used if ws too small
// ============================================================
__device__ __forceinline__ void stage_rope_row_fb(const float* __restrict__ src,
                                                  u16 (*dst)[72],
                                                  int n_global, int sr, int d0)
{
  const float4* g = (const float4*)src;
  float4 a0 = g[0], a1 = g[1], a2 = g[2], a3 = g[3];
  float xx[16] = {a0.x,a0.y,a0.z,a0.w, a1.x,a1.y,a1.z,a1.w,
                  a2.x,a2.y,a2.z,a2.w, a3.x,a3.y,a3.z,a3.w};
  uint32_t w[8];
  #pragma unroll
  for (int j=0;j<8;++j){
    int i = (d0>>1)+j;
    float inv = exp2f(-(float)i * ROPE_K);
    float ang = (float)n_global * inv;
    float sn, cs; sincosf(ang, &sn, &cs);
    float x0 = xx[2*j], x1 = xx[2*j+1];
    float q0 = x0*cs - x1*sn;
    float q1 = x1*cs + x0*sn;
    w[j] = f2bf(q0) | (f2bf(q1)<<16);
  }
  *(uint4*)&dst[sr][d0]   = make_uint4(w[0],w[1],w[2],w[3]);
  *(uint4*)&dst[sr][d0+8] = make_uint4(w[4],w[5],w[6],w[7]);
}

__global__ __launch_bounds__(256,2) void attn_fallback(
    const float* __restrict__ xq, const float* __restrict__ xk,
    const float* __restrict__ xv, const int* __restrict__ vis,
    float* __restrict__ out)
{
  __shared__ u16 Qs[64][72];
  __shared__ u16 Ks[64][72];
  __shared__ u16 Vt[64][72];
  __shared__ u16 Ps[4][16][72];
  __shared__ float viss[64];

  const int tid  = threadIdx.x;
  const int wave = tid >> 6;
  const int lane = tid & 63;
  const int l15  = lane & 15;
  const int quad = lane >> 4;

  const int bid = blockIdx.x;
  const int qt = bid & 15;
  const int h  = (bid >> 4) & 7;
  const int b  = bid >> 7;

  const int sr = tid >> 2;
  const int d0 = (tid & 3) << 4;

  {
    int ng = (qt<<6) + sr;
    const float* src = xq + ((((size_t)b*Nn + ng)*Hh + h)<<6) + d0;
    stage_rope_row_fb(src, Qs, ng, sr, d0);
  }
  __syncthreads();

  short8 qa0 = *(const short8*)&Qs[(wave<<4)+l15][quad<<3];
  short8 qa1 = *(const short8*)&Qs[(wave<<4)+l15][(quad<<3)+32];

  f32x4 acc[4];
  #pragma unroll
  for (int s=0;s<4;++s) acc[s] = (f32x4){0.f,0.f,0.f,0.f};
  float m_r[4], l_r[4];
  #pragma unroll
  for (int rr=0;rr<4;++rr){ m_r[rr] = -1e30f; l_r[rr] = 0.f; }

  for (int kt=0; kt<16; ++kt){
    __syncthreads();
    {
      int ng = (kt<<6) + sr;
      const float* src = xk + ((((size_t)b*Nn + ng)*Hh + h)<<6) + d0;
      stage_rope_row_fb(src, Ks, ng, sr, d0);
    }
    {
      int ng = (kt<<6) + sr;
      const float4* g = (const float4*)(xv + ((((size_t)b*Nn + ng)*Hh + h)<<6) + d0);
      float4 a0 = g[0], a1 = g[1], a2 = g[2], a3 = g[3];
      float vv16[16] = {a0.x,a0.y,a0.z,a0.w, a1.x,a1.y,a1.z,a1.w,
                        a2.x,a2.y,a2.z,a2.w, a3.x,a3.y,a3.z,a3.w};
      #pragma unroll
      for (int j=0;j<16;++j) Vt[d0+j][sr] = (u16)f2bf(vv16[j]);
    }
    if (tid < 64) viss[tid] = (vis[b*Nn + (kt<<6) + tid] != 0) ? 1.f : 0.f;
    __syncthreads();

    f32x4 s4[4];
    #pragma unroll
    for (int n=0;n<4;++n){
      short8 kb0 = *(const short8*)&Ks[(n<<4)+l15][quad<<3];
      short8 kb1 = *(const short8*)&Ks[(n<<4)+l15][(quad<<3)+32];
      f32x4 t = (f32x4){0.f,0.f,0.f,0.f};
      t = mfma16(qa0, kb0, t);
      t = mfma16(qa1, kb1, t);
      s4[n] = t;
    }
    float vv[4];
    #pragma unroll
    for (int n=0;n<4;++n) vv[n] = viss[(n<<4)+l15];

    float p[4][4];
    #pragma unroll
    for (int rr=0; rr<4; ++rr){
      float sc[4];
      #pragma unroll
      for (int n=0;n<4;++n) sc[n] = (vv[n] > 0.f) ? s4[n][rr]*0.125f : -1e30f;
      float tm = fmaxf(fmaxf(sc[0],sc[1]), fmaxf(sc[2],sc[3]));
      tm = fmaxf(tm, __shfl_xor(tm,1));
      tm = fmaxf(tm, __shfl_xor(tm,2));
      tm = fmaxf(tm, __shfl_xor(tm,4));
      tm = fmaxf(tm, __shfl_xor(tm,8));
      float mnew  = fmaxf(m_r[rr], tm);
      float alpha = __expf(m_r[rr] - mnew);
      m_r[rr] = mnew;
      float psum = 0.f;
      #pragma unroll
      for (int n=0;n<4;++n){
        float pv = (vv[n] > 0.f) ? __expf(sc[n] - mnew) : 0.f;
        p[n][rr] = pv; psum += pv;
      }
      l_r[rr] = l_r[rr]*alpha + psum;
      #pragma unroll
      for (int s=0;s<4;++s) acc[s][rr] *= alpha;
    }

    #pragma unroll
    for (int n=0;n<4;++n)
      #pragma unroll
      for (int rr=0;rr<4;++rr)
        Ps[wave][(quad<<2)+rr][(n<<4)+l15] = (u16)f2bf(p[n][rr]);
    asm volatile("s_waitcnt lgkmcnt(0)" ::: "memory");
    short8 pa0 = *(const short8*)&Ps[wave][l15][quad<<3];
    short8 pa1 = *(const short8*)&Ps[wave][l15][(quad<<3)+32];

    #pragma unroll
    for (int s=0;s<4;++s){
      short8 vb0 = *(const short8*)&Vt[(s<<4)+l15][quad<<3];
      short8 vb1 = *(const short8*)&Vt[(s<<4)+l15][(quad<<3)+32];
      acc[s] = mfma16(pa0, vb0, acc[s]);
      acc[s] = mfma16(pa1, vb1, acc[s]);
    }
  }

  #pragma unroll
  for (int rr=0;rr<4;++rr){
    float t = l_r[rr];
    t += __shfl_xor(t,1); t += __shfl_xor(t,2);
    t += __shfl_xor(t,4); t += __shfl_xor(t,8);
    int row = (qt<<6) + (wave<<4) + (quad<<2) + rr;
    int qv  = vis[b*Nn + row];
    float invl = (qv != 0 && t > 0.f) ? 1.f/t : 0.f;
    size_t obase = (((size_t)b*Nn + row)*Hh + h) << 6;
    #pragma unroll
    for (int s=0;s<4;++s)
      out[obase + (s<<4) + l15] = acc[s][rr]*invl;
  }
}

extern "C" void kernel_launch(void* const* d_in, const int* in_sizes, int n_in,
                              void* d_out, int out_size, void* d_ws, size_t ws_size,
                              hipStream_t stream)
{
  const float* xq = (const float*)d_in[0];
  const float* xk = (const float*)d_in[1];
  const float* xv = (const float*)d_in[2];
  const int* vis  = (const int*)d_in[3];
  float* out = (float*)d_out;

  const size_t kv_elems = (size_t)Bb*Hh*Nn*Dd;            // 8.39M
  const size_t kv_bytes = kv_elems*sizeof(u16);           // 16.78 MB
  const size_t tab_bytes = (size_t)Nn*32*sizeof(float2);  // 256 KB
  const size_t need_tab = tab_bytes + 2*kv_bytes;
  const size_t need_kv  = 2*kv_bytes;

  if (d_ws != nullptr && ws_size >= need_tab){
    float2* tab = (float2*)d_ws;
    u16* Kf = (u16*)((char*)d_ws + tab_bytes);
    u16* Vf = Kf + kv_elems;
    rope_table_kernel<<<dim3((Nn*32)/256), dim3(256), 0, stream>>>(tab);
    prepass_kernel<<<dim3(Bb*Hh*(Nn/64)), dim3(256), 0, stream>>>(xk, xv, tab, Kf, Vf);
    attn7_kernel<<<dim3(Bb*Hh*(Nn/128)), dim3(256), 0, stream>>>(xq, Kf, Vf, vis, tab, out);
  } else if (d_ws != nullptr && ws_size >= need_kv){
    u16* Kf = (u16*)d_ws;
    u16* Vf = Kf + kv_elems;
    prepass_kernel<<<dim3(Bb*Hh*(Nn/64)), dim3(256), 0, stream>>>(xk, xv, nullptr, Kf, Vf);
    attn7_kernel<<<dim3(Bb*Hh*(Nn/128)), dim3(256), 0, stream>>>(xq, Kf, Vf, vis, nullptr, out);
  } else {
    attn_fallback<<<dim3(Bb*Hh*(Nn/64)), dim3(256), 0, stream>>>(xq, xk, xv, vis, out);
  }
}

// Round 9
// 189.457 us; speedup vs baseline: 1.1002x; 1.1002x over previous
//
#include <hip/hip_runtime.h>
#include <hip/hip_bf16.h>
#include <stdint.h>

#define Bb 16
#define Nn 1024
#define Hh 8
#define Dd 64

typedef unsigned short u16;
typedef float f32x4 __attribute__((ext_vector_type(4)));
typedef short short8 __attribute__((ext_vector_type(8)));

union U4S8 { uint4 u; short8 s; };
union BF2U { __hip_bfloat162 h; uint32_t u; };

__device__ __forceinline__ uint32_t f2bf(float f){
  union{float f;uint32_t i;} v; v.f=f;
  return (v.i + 0x7fffu + ((v.i>>16)&1u))>>16;
}

__device__ __forceinline__ f32x4 mfma16(short8 a, short8 b, f32x4 c){
  return __builtin_amdgcn_mfma_f32_16x16x32_bf16(a,b,c,0,0,0);
}

// async global->LDS, 16B per lane; LDS dst must be wave-uniform base + lane*16
typedef __attribute__((address_space(3))) uint32_t lds_u32;
typedef const __attribute__((address_space(1))) uint32_t glb_u32;
__device__ __forceinline__ void gl_lds16(const u16* g, u16* l){
  __builtin_amdgcn_global_load_lds((glb_u32*)g, (lds_u32*)l, 16, 0, 0);
}

// log2(10000)/32
#define ROPE_K 0.41524101186092030f
// 0.125 * log2(e)  (sm_scale folded with exp->exp2 conversion)
#define QS 0.18033688011112042f
#define NEGBIG -1.0e30f

// ============================================================
// Prepass -> fragment-linear layouts (per (bh,kt) block of 4096 u16):
//   Kf elem = kb*1024 + half*512 + quad*128 + l15*8 + j
//     holds K[key=kb*16+l15][d=half*32+quad*8+j] (roped)
//   Vf elem = s*1024 + half*512 + qd*128 + l15v*8 + j
//     holds V[d=s*16+l15v][slot=half*32+qd*8+j], slot(k) permutation:
//     slot = (k&1) | ((k>>4)&3)<<1 | ((k>>2)&3)<<3 | ((k>>1)&1)<<5
// ============================================================
__global__ __launch_bounds__(256) void prepass_kernel(
    const float* __restrict__ xk, const float* __restrict__ xv,
    u16* __restrict__ Kf, u16* __restrict__ Vf)
{
  const int tid = threadIdx.x;
  const int bid = blockIdx.x;
  const int nt = bid & 15, h = (bid>>4)&7, b = bid>>7;
  const size_t bh = (size_t)b*Hh + h;
  const size_t tile = (bh<<4) + nt;            // (bh*16 + kt) blocks of 4096

  // ---- K rope -> fragment-linear ----
  {
    int r = tid>>2, c = (tid&3)<<4;
    int n = (nt<<6) + r;
    const float4* g = (const float4*)(xk + ((((size_t)b*Nn + n)*Hh + h)<<6) + c);
    float4 a0=g[0],a1=g[1],a2=g[2],a3=g[3];
    float xx[16] = {a0.x,a0.y,a0.z,a0.w, a1.x,a1.y,a1.z,a1.w,
                    a2.x,a2.y,a2.z,a2.w, a3.x,a3.y,a3.z,a3.w};
    uint32_t w[8];
    #pragma unroll
    for (int j=0;j<8;++j){
      int i = (c>>1)+j;
      float inv = exp2f(-(float)i * ROPE_K);
      float ang = (float)n * inv;
      float sn, cs; sincosf(ang, &sn, &cs);
      float x0 = xx[2*j], x1 = xx[2*j+1];
      float q0 = x0*cs - x1*sn;
      float q1 = x1*cs + x0*sn;
      w[j] = f2bf(q0) | (f2bf(q1)<<16);
    }
    int kb = r>>4, l15 = r&15;
    int half = c>>5, qd = (c>>3)&3;
    u16* base = Kf + (tile<<12);
    int dest0 = (kb<<10) + (half<<9) + (qd<<7) + (l15<<3);
    *(uint4*)(base + dest0)       = make_uint4(w[0],w[1],w[2],w[3]);
    *(uint4*)(base + dest0 + 128) = make_uint4(w[4],w[5],w[6],w[7]);
  }

  // ---- V transpose + key permute -> fragment-linear ----
  {
    int k = tid&63, ds = (tid>>6)<<4;
    int n = (nt<<6) + k;
    int slot = (k&1) | (((k>>4)&3)<<1) | (((k>>2)&3)<<3) | (((k>>1)&1)<<5);
    int half = slot>>5, qd = (slot>>3)&3, j = slot&7;
    const float4* g = (const float4*)(xv + ((((size_t)b*Nn + n)*Hh + h)<<6) + ds);
    float4 a0=g[0],a1=g[1],a2=g[2],a3=g[3];
    float vv[16] = {a0.x,a0.y,a0.z,a0.w, a1.x,a1.y,a1.z,a1.w,
                    a2.x,a2.y,a2.z,a2.w, a3.x,a3.y,a3.z,a3.w};
    u16* base = Vf + (tile<<12);
    #pragma unroll
    for (int jj=0;jj<16;++jj){
      int d = ds + jj;
      int s = d>>4, l15v = d&15;
      base[(s<<10) + (half<<9) + (qd<<7) + (l15v<<3) + j] = (u16)f2bf(vv[jj]);
    }
  }
}

// ============================================================
// Main attention: 512 blocks = (b,h,qt of 256 rows), 256 threads,
// wave owns 64 q rows (4 m-blocks) -> LDS fragment reads amortized
// 4x vs mb=2 (the LDS pipe was the R5-R7 wall; wave-private streaming
// hits the L2-BW wall instead -> block sharing + fewer wave-kts).
// DMA double-buffer staging, fragment-linear (conflict-free), XCD-
// aware swizzle (L2-resident K/V), mask in MFMA C-bias, l via
// ones-MFMA, register-only P transform.
// ============================================================
__global__ __launch_bounds__(256,2) void attn8_kernel(
    const float* __restrict__ xq, const u16* __restrict__ Kf,
    const u16* __restrict__ Vf, const int* __restrict__ vis,
    float* __restrict__ out)
{
  __shared__ u16 KV[2][2][4096];    // [buf][K/V][frag-linear], 32 KiB

  const int tid  = threadIdx.x;
  const int lane = tid & 63;
  const int wave = tid >> 6;
  const int l15  = lane & 15;
  const int quad = lane >> 4;

  // ---- XCD-aware block decode (grid = 512, 8 XCDs, 64 blocks/XCD) ----
  const int bid = blockIdx.x;
  const int xcd = bid & 7;          // consecutive bids round-robin XCDs
  const int i   = bid >> 3;         // 0..63 within this XCD
  const int bh_ = (xcd<<4) | (i>>2);// 16 bh per XCD, 4 qt-blocks adjacent
  const int qt  = i & 3;
  const int h   = bh_ & 7;
  const int b   = bh_ >> 3;
  const size_t bh = (size_t)bh_;
  const int qbase = qt<<8;          // 256 q rows per block

  const int* visb = vis + b*Nn;
  const u16* Kfb = Kf + (bh<<16);   // 16 tiles * 4096
  const u16* Vfb = Vf + (bh<<16);

  // ---- roped Q B-frags in registers (QS folded), 4 m-blocks ----
  short8 qa[4][2];
  #pragma unroll
  for (int mb=0; mb<4; ++mb){
    int n = qbase + (wave<<6) + (mb<<4) + l15;
    const float* src = xq + ((((size_t)b*Nn + n)*Hh + h)<<6);
    #pragma unroll
    for (int half=0; half<2; ++half){
      int d0 = (half<<5) + (quad<<3);
      const float4* g = (const float4*)(src + d0);
      float4 u0 = g[0], u1 = g[1];
      float xx[8] = {u0.x,u0.y,u0.z,u0.w, u1.x,u1.y,u1.z,u1.w};
      uint32_t w[4];
      #pragma unroll
      for (int j=0;j<4;++j){
        int i2 = (d0>>1) + j;
        float inv = exp2f(-(float)i2 * ROPE_K);
        float ang = (float)n * inv;
        float sn, cs; sincosf(ang, &sn, &cs);
        float x0 = xx[2*j], x1 = xx[2*j+1];
        float q0 = (x0*cs - x1*sn)*QS;
        float q1 = (x1*cs + x0*sn)*QS;
        w[j] = f2bf(q0) | (f2bf(q1)<<16);
      }
      U4S8 t; t.u = make_uint4(w[0],w[1],w[2],w[3]);
      qa[mb][half] = t.s;
    }
  }

  U4S8 ones_u; ones_u.u = make_uint4(0x3F803F80u,0x3F803F80u,0x3F803F80u,0x3F803F80u);
  const short8 ones = ones_u.s;

  f32x4 acc[4][4];                  // [mb][d-block]
  f32x4 l_acc[4];
  #pragma unroll
  for (int mb=0;mb<4;++mb){
    l_acc[mb] = (f32x4){0.f,0.f,0.f,0.f};
    #pragma unroll
    for (int s=0;s<4;++s) acc[mb][s] = (f32x4){0.f,0.f,0.f,0.f};
  }

  const int t8 = tid<<3;            // elem offset = tid*16B

  // ---- stage kt=0 into buf 0 ----
  gl_lds16(Kfb + t8,        &KV[0][0][t8]);
  gl_lds16(Kfb + 2048 + t8, &KV[0][0][2048 + t8]);
  gl_lds16(Vfb + t8,        &KV[0][1][t8]);
  gl_lds16(Vfb + 2048 + t8, &KV[0][1][2048 + t8]);
  __syncthreads();

  for (int kt=0; kt<16; ++kt){
    const int cur = kt & 1;
    // ---- issue async stage of kt+1 into the other buffer ----
    if (kt < 15){
      const u16* kg = Kfb + ((kt+1)<<12);
      const u16* vg = Vfb + ((kt+1)<<12);
      gl_lds16(kg + t8,        &KV[cur^1][0][t8]);
      gl_lds16(kg + 2048 + t8, &KV[cur^1][0][2048 + t8]);
      gl_lds16(vg + t8,        &KV[cur^1][1][t8]);
      gl_lds16(vg + 2048 + t8, &KV[cur^1][1][2048 + t8]);
    }

    // ---- S^T = K Q^T per kb (bias C-init = mask), exp2+pack in-register ----
    uint32_t pk[4][2][4];           // [kb][h][mb]
    #pragma unroll
    for (int kb=0;kb<4;++kb){
      short8 kf0 = *(const short8*)&KV[cur][0][(kb<<10) + (lane<<3)];
      short8 kf1 = *(const short8*)&KV[cur][0][(kb<<10) + 512 + (lane<<3)];
      int4 vi = *(const int4*)&visb[(kt<<6)+(kb<<4)+(quad<<2)];
      f32x4 bias;
      bias.x = vi.x ? 0.f : NEGBIG;
      bias.y = vi.y ? 0.f : NEGBIG;
      bias.z = vi.z ? 0.f : NEGBIG;
      bias.w = vi.w ? 0.f : NEGBIG;
      #pragma unroll
      for (int mb=0;mb<4;++mb){
        f32x4 t = mfma16(kf0, qa[mb][0], bias);
        t = mfma16(kf1, qa[mb][1], t);
        // lane holds S^T[key=kb*16+quad*4+rr][q=mb*16+l15], log2-domain
        float p0 = __builtin_amdgcn_exp2f(t.x);
        float p1 = __builtin_amdgcn_exp2f(t.y);
        float p2 = __builtin_amdgcn_exp2f(t.z);
        float p3 = __builtin_amdgcn_exp2f(t.w);
        BF2U e0; e0.h = __float22bfloat162_rn(make_float2(p0,p1));
        BF2U e1; e1.h = __float22bfloat162_rn(make_float2(p2,p3));
        pk[kb][0][mb] = e0.u;
        pk[kb][1][mb] = e1.u;
      }
    }

    // ---- assemble P A-frags (pure register repack) ----
    short8 pa[4][2];
    #pragma unroll
    for (int mb=0;mb<4;++mb){
      U4S8 a0; a0.u = make_uint4(pk[0][0][mb], pk[1][0][mb], pk[2][0][mb], pk[3][0][mb]);
      U4S8 a1; a1.u = make_uint4(pk[0][1][mb], pk[1][1][mb], pk[2][1][mb], pk[3][1][mb]);
      pa[mb][0] = a0.s; pa[mb][1] = a1.s;
    }

    // ---- l += P * ones (matrix pipe), O += P V ----
    #pragma unroll
    for (int mb=0;mb<4;++mb){
      l_acc[mb] = mfma16(pa[mb][0], ones, l_acc[mb]);
      l_acc[mb] = mfma16(pa[mb][1], ones, l_acc[mb]);
    }
    #pragma unroll
    for (int s=0;s<4;++s){
      short8 vb0 = *(const short8*)&KV[cur][1][(s<<10) + (lane<<3)];
      short8 vb1 = *(const short8*)&KV[cur][1][(s<<10) + 512 + (lane<<3)];
      #pragma unroll
      for (int mb=0;mb<4;++mb){
        acc[mb][s] = mfma16(pa[mb][0], vb0, acc[mb][s]);
        acc[mb][s] = mfma16(pa[mb][1], vb1, acc[mb][s]);
      }
    }

    __syncthreads();  // drains kt+1 loads (issued a full compute phase ago)
  }

  // ---- epilogue: l already per-q in C layout; normalize + store ----
  #pragma unroll
  for (int mb=0;mb<4;++mb){
    int4 qvi = *(const int4*)&visb[qbase + (wave<<6) + (mb<<4) + (quad<<2)];
    int qv[4] = {qvi.x, qvi.y, qvi.z, qvi.w};
    #pragma unroll
    for (int rr=0;rr<4;++rr){
      float lq = l_acc[mb][rr];
      float invl = (qv[rr] != 0 && lq > 0.f) ? 1.f/lq : 0.f;
      int qrow = qbase + (wave<<6) + (mb<<4) + (quad<<2) + rr;
      float* ob = out + ((((size_t)b*Nn + qrow)*Hh + h)<<6);
      #pragma unroll
      for (int s=0;s<4;++s)
        ob[(s<<4)+l15] = acc[mb][s][rr]*invl;
    }
  }
}

// ============================================================
// Fallback (R2 kernel, inline sincos) — used if ws too small
// ============================================================
__device__ __forceinline__ void stage_rope_row_fb(const float* __restrict__ src,
                                                  u16 (*dst)[72],
                                                  int n_global, int sr, int d0)
{
  const float4* g = (const float4*)src;
  float4 a0 = g[0], a1 = g[1], a2 = g[2], a3 = g[3];
  float xx[16] = {a0.x,a0.y,a0.z,a0.w, a1.x,a1.y,a1.z,a1.w,
                  a2.x,a2.y,a2.z,a2.w, a3.x,a3.y,a3.z,a3.w};
  uint32_t w[8];
  #pragma unroll
  for (int j=0;j<8;++j){
    int i = (d0>>1)+j;
    float inv = exp2f(-(float)i * ROPE_K);
    float ang = (float)n_global * inv;
    float sn, cs; sincosf(ang, &sn, &cs);
    float x0 = xx[2*j], x1 = xx[2*j+1];
    float q0 = x0*cs - x1*sn;
    float q1 = x1*cs + x0*sn;
    w[j] = f2bf(q0) | (f2bf(q1)<<16);
  }
  *(uint4*)&dst[sr][d0]   = make_uint4(w[0],w[1],w[2],w[3]);
  *(uint4*)&dst[sr][d0+8] = make_uint4(w[4],w[5],w[6],w[7]);
}

__global__ __launch_bounds__(256,2) void attn_fallback(
    const float* __restrict__ xq, const float* __restrict__ xk,
    const float* __restrict__ xv, const int* __restrict__ vis,
    float* __restrict__ out)
{
  __shared__ u16 Qs[64][72];
  __shared__ u16 Ks[64][72];
  __shared__ u16 Vt[64][72];
  __shared__ u16 Ps[4][16][72];
  __shared__ float viss[64];

  const int tid  = threadIdx.x;
  const int wave = tid >> 6;
  const int lane = tid & 63;
  const int l15  = lane & 15;
  const int quad = lane >> 4;

  const int bid = blockIdx.x;
  const int qt = bid & 15;
  const int h  = (bid >> 4) & 7;
  const int b  = bid >> 7;

  const int sr = tid >> 2;
  const int d0 = (tid & 3) << 4;

  {
    int ng = (qt<<6) + sr;
    const float* src = xq + ((((size_t)b*Nn + ng)*Hh + h)<<6) + d0;
    stage_rope_row_fb(src, Qs, ng, sr, d0);
  }
  __syncthreads();

  short8 qa0 = *(const short8*)&Qs[(wave<<4)+l15][quad<<3];
  short8 qa1 = *(const short8*)&Qs[(wave<<4)+l15][(quad<<3)+32];

  f32x4 acc[4];
  #pragma unroll
  for (int s=0;s<4;++s) acc[s] = (f32x4){0.f,0.f,0.f,0.f};
  float m_r[4], l_r[4];
  #pragma unroll
  for (int rr=0;rr<4;++rr){ m_r[rr] = -1e30f; l_r[rr] = 0.f; }

  for (int kt=0; kt<16; ++kt){
    __syncthreads();
    {
      int ng = (kt<<6) + sr;
      const float* src = xk + ((((size_t)b*Nn + ng)*Hh + h)<<6) + d0;
      stage_rope_row_fb(src, Ks, ng, sr, d0);
    }
    {
      int ng = (kt<<6) + sr;
      const float4* g = (const float4*)(xv + ((((size_t)b*Nn + ng)*Hh + h)<<6) + d0);
      float4 a0 = g[0], a1 = g[1], a2 = g[2], a3 = g[3];
      float vv16[16] = {a0.x,a0.y,a0.z,a0.w, a1.x,a1.y,a1.z,a1.w,
                        a2.x,a2.y,a2.z,a2.w, a3.x,a3.y,a3.z,a3.w};
      #pragma unroll
      for (int j=0;j<16;++j) Vt[d0+j][sr] = (u16)f2bf(vv16[j]);
    }
    if (tid < 64) viss[tid] = (vis[b*Nn + (kt<<6) + tid] != 0) ? 1.f : 0.f;
    __syncthreads();

    f32x4 s4[4];
    #pragma unroll
    for (int n=0;n<4;++n){
      short8 kb0 = *(const short8*)&Ks[(n<<4)+l15][quad<<3];
      short8 kb1 = *(const short8*)&Ks[(n<<4)+l15][(quad<<3)+32];
      f32x4 t = (f32x4){0.f,0.f,0.f,0.f};
      t = mfma16(qa0, kb0, t);
      t = mfma16(qa1, kb1, t);
      s4[n] = t;
    }
    float vv[4];
    #pragma unroll
    for (int n=0;n<4;++n) vv[n] = viss[(n<<4)+l15];

    float p[4][4];
    #pragma unroll
    for (int rr=0; rr<4; ++rr){
      float sc[4];
      #pragma unroll
      for (int n=0;n<4;++n) sc[n] = (vv[n] > 0.f) ? s4[n][rr]*0.125f : -1e30f;
      float tm = fmaxf(fmaxf(sc[0],sc[1]), fmaxf(sc[2],sc[3]));
      tm = fmaxf(tm, __shfl_xor(tm,1));
      tm = fmaxf(tm, __shfl_xor(tm,2));
      tm = fmaxf(tm, __shfl_xor(tm,4));
      tm = fmaxf(tm, __shfl_xor(tm,8));
      float mnew  = fmaxf(m_r[rr], tm);
      float alpha = __expf(m_r[rr] - mnew);
      m_r[rr] = mnew;
      float psum = 0.f;
      #pragma unroll
      for (int n=0;n<4;++n){
        float pv = (vv[n] > 0.f) ? __expf(sc[n] - mnew) : 0.f;
        p[n][rr] = pv; psum += pv;
      }
      l_r[rr] = l_r[rr]*alpha + psum;
      #pragma unroll
      for (int s=0;s<4;++s) acc[s][rr] *= alpha;
    }

    #pragma unroll
    for (int n=0;n<4;++n)
      #pragma unroll
      for (int rr=0;rr<4;++rr)
        Ps[wave][(quad<<2)+rr][(n<<4)+l15] = (u16)f2bf(p[n][rr]);
    asm volatile("s_waitcnt lgkmcnt(0)" ::: "memory");
    short8 pa0 = *(const short8*)&Ps[wave][l15][quad<<3];
    short8 pa1 = *(const short8*)&Ps[wave][l15][(quad<<3)+32];

    #pragma unroll
    for (int s=0;s<4;++s){
      short8 vb0 = *(const short8*)&Vt[(s<<4)+l15][quad<<3];
      short8 vb1 = *(const short8*)&Vt[(s<<4)+l15][(quad<<3)+32];
      acc[s] = mfma16(pa0, vb0, acc[s]);
      acc[s] = mfma16(pa1, vb1, acc[s]);
    }
  }

  #pragma unroll
  for (int rr=0;rr<4;++rr){
    float t = l_r[rr];
    t += __shfl_xor(t,1); t += __shfl_xor(t,2);
    t += __shfl_xor(t,4); t += __shfl_xor(t,8);
    int row = (qt<<6) + (wave<<4) + (quad<<2) + rr;
    int qv  = vis[b*Nn + row];
    float invl = (qv != 0 && t > 0.f) ? 1.f/t : 0.f;
    size_t obase = (((size_t)b*Nn + row)*Hh + h) << 6;
    #pragma unroll
    for (int s=0;s<4;++s)
      out[obase + (s<<4) + l15] = acc[s][rr]*invl;
  }
}

extern "C" void kernel_launch(void* const* d_in, const int* in_sizes, int n_in,
                              void* d_out, int out_size, void* d_ws, size_t ws_size,
                              hipStream_t stream)
{
  const float* xq = (const float*)d_in[0];
  const float* xk = (const float*)d_in[1];
  const float* xv = (const float*)d_in[2];
  const int* vis  = (const int*)d_in[3];
  float* out = (float*)d_out;

  const size_t kv_elems = (size_t)Bb*Hh*Nn*Dd;            // 8.39M
  const size_t kv_bytes = kv_elems*sizeof(u16);           // 16.78 MB
  const size_t need_kv  = 2*kv_bytes;                     // 33.6 MB

  if (d_ws != nullptr && ws_size >= need_kv){
    u16* Kf = (u16*)d_ws;
    u16* Vf = Kf + kv_elems;
    prepass_kernel<<<dim3(Bb*Hh*(Nn/64)), dim3(256), 0, stream>>>(xk, xv, Kf, Vf);
    attn8_kernel<<<dim3(Bb*Hh*(Nn/256)), dim3(256), 0, stream>>>(xq, Kf, Vf, vis, out);
  } else {
    attn_fallback<<<dim3(Bb*Hh*(Nn/64)), dim3(256), 0, stream>>>(xq, xk, xv, vis, out);
  }
}